// Round 6
// baseline (118.577 us; speedup 1.0000x reference)
//
#include <hip/hip_runtime.h>
#include <hip/hip_bf16.h>

// Problem constants
#define K_DIM 4096
#define N_DIM 14336
#define M_DIM 256
#define BM 64
#define BN 64
#define BK 64
#define NPH 64          // K_DIM / BK phases
#define RS 72           // W row stride in shorts (144 B, 16B-aligned rows)

typedef __attribute__((ext_vector_type(4))) float f32x4;
typedef __attribute__((ext_vector_type(8))) short short8;

__device__ __forceinline__ unsigned short f2bf(float f) {
    union { float f; unsigned u; } v; v.f = f;
    unsigned r = v.u + 0x7fffu + ((v.u >> 16) & 1u);   // RNE
    return (unsigned short)(r >> 16);
}

// Barrier that does NOT force vmcnt(0): LDS visibility + counted vmem drain.
// Keeps the 18-load q prefetch set in flight across the barrier (T4).
#define KBAR(N) do { \
    asm volatile("s_waitcnt lgkmcnt(0)" ::: "memory");     \
    asm volatile("s_waitcnt vmcnt(" #N ")" ::: "memory");  \
    __builtin_amdgcn_s_barrier();                           \
} while (0)

// Pre-convert x (fp32 [256][4096]) into bf16 MFMA-A-fragment order:
// chunk = ktile*16 + mtile; lane l of chunk holds
// 8 bf16 = x[mtile*16 + (l&15)][ktile*32 + (l>>4)*8 .. +8]  (1 KB per chunk)
__global__ void convert_x_kernel(const float* __restrict__ x,
                                 unsigned short* __restrict__ xf) {
    int t = blockIdx.x * blockDim.x + threadIdx.x;   // 0..131071
    int chunk = t >> 6;
    int lane  = t & 63;
    int ktile = chunk >> 4;
    int mtile = chunk & 15;
    int m = mtile * 16 + (lane & 15);
    int k = ktile * 32 + ((lane >> 4) << 3);
    const float* xp = x + (size_t)m * K_DIM + k;
    float4 lo = *(const float4*)xp;
    float4 hi = *(const float4*)(xp + 4);
    union { unsigned short s[8]; int4 v; } o;
    o.s[0] = f2bf(lo.x); o.s[1] = f2bf(lo.y); o.s[2] = f2bf(lo.z); o.s[3] = f2bf(lo.w);
    o.s[4] = f2bf(hi.x); o.s[5] = f2bf(hi.y); o.s[6] = f2bf(hi.z); o.s[7] = f2bf(hi.w);
    *(int4*)(xf + ((size_t)t << 3)) = o.v;
}

// v8: 896 blocks x 256 thr (4 waves = 2m x 2n), 64x64 tile, 18 KB LDS,
// VGPR < 128 -> 4 blocks/CU co-resident (grid avg 3.5) for wave-level
// latency coverage (m114). q -> two static register sets; barriers never
// drain the prefetch (counted vmcnt). One barrier per K-phase.
__global__ __launch_bounds__(256, 4)
void plq_gemm_v8(const unsigned short* __restrict__ xf,
                 const int* __restrict__ q,
                 const float* __restrict__ qs,
                 const float* __restrict__ qb,
                 const float* __restrict__ bias,
                 float* __restrict__ out)
{
    __shared__ unsigned short w0[BN * RS];   // W tile (even phases read)
    __shared__ unsigned short w1[BN * RS];   // W tile (odd phases read)

    const int tid  = threadIdx.x;
    const int lane = tid & 63;
    const int wv   = tid >> 6;          // 0..3
    const int wm   = wv >> 1;           // m-half of block tile
    const int wn   = wv & 1;            // n-half of block tile

    // XCD-chunked remap: 896 = 8 XCDs x 112; the 4 m-tiles sharing one
    // n-range are gid-adjacent on the same XCD -> q 4-way reuse is L2-hit.
    const int gid = (blockIdx.x & 7) * 112 + (blockIdx.x >> 3);
    const int mt  = gid & 3;                 // m-tile 0..3 (64 rows each)
    const int n0  = (gid >> 2) * BN;         // n-tile 0..223

    // q staging: thread -> column qn (64 lanes = 64 cols = 256B coalesced),
    // 16 consecutive k rows starting at qk0.
    const int qn   = tid & 63;
    const int qk0  = (tid >> 6) << 4;        // 0,16,32,48
    const size_t qcol = (size_t)n0 + qn;

    f32x4 acc[2][2] = {};
    short8 af[2][2];                         // [ks][mf] A fragments
    int   qA[16], qB[16];
    float sA, zA, sB, zB;

    auto issueQA = [&](int t) {
        const int* p = q + (size_t)(t * BK + qk0) * N_DIM + qcol;
        #pragma unroll
        for (int j = 0; j < 16; ++j) qA[j] = p[(size_t)j * N_DIM];
        const int g = t >> 1;                // BK=64: group = phase/2
        sA = qs[(size_t)g * N_DIM + qcol];
        zA = qb[(size_t)g * N_DIM + qcol];
    };
    auto issueQB = [&](int t) {
        const int* p = q + (size_t)(t * BK + qk0) * N_DIM + qcol;
        #pragma unroll
        for (int j = 0; j < 16; ++j) qB[j] = p[(size_t)j * N_DIM];
        const int g = t >> 1;
        sB = qs[(size_t)g * N_DIM + qcol];
        zB = qb[(size_t)g * N_DIM + qcol];
    };
    auto deqA = [&](unsigned short* dst) {   // qA -> 16 bf16 -> 2 ds_write_b128
        union { unsigned u[4]; int4 v; } p0, p1;
        #pragma unroll
        for (int j = 0; j < 4; ++j) {
            float f0 = (float)qA[2*j]     * sA + zA;
            float f1 = (float)qA[2*j+1]   * sA + zA;
            float f2 = (float)qA[8+2*j]   * sA + zA;
            float f3 = (float)qA[8+2*j+1] * sA + zA;
            p0.u[j] = (unsigned)f2bf(f0) | ((unsigned)f2bf(f1) << 16);
            p1.u[j] = (unsigned)f2bf(f2) | ((unsigned)f2bf(f3) << 16);
        }
        *(int4*)&dst[qn * RS + qk0]     = p0.v;
        *(int4*)&dst[qn * RS + qk0 + 8] = p1.v;
    };
    auto deqB = [&](unsigned short* dst) {
        union { unsigned u[4]; int4 v; } p0, p1;
        #pragma unroll
        for (int j = 0; j < 4; ++j) {
            float f0 = (float)qB[2*j]     * sB + zB;
            float f1 = (float)qB[2*j+1]   * sB + zB;
            float f2 = (float)qB[8+2*j]   * sB + zB;
            float f3 = (float)qB[8+2*j+1] * sB + zB;
            p0.u[j] = (unsigned)f2bf(f0) | ((unsigned)f2bf(f1) << 16);
            p1.u[j] = (unsigned)f2bf(f2) | ((unsigned)f2bf(f3) << 16);
        }
        *(int4*)&dst[qn * RS + qk0]     = p0.v;
        *(int4*)&dst[qn * RS + qk0 + 8] = p1.v;
    };
    auto loadAfr = [&](int i) {              // 4 x 16B loads from xf (L2-hot)
        #pragma unroll
        for (int ks = 0; ks < 2; ++ks)
            #pragma unroll
            for (int mf = 0; mf < 2; ++mf) {
                const int ktile = i * 2 + ks;
                const int mtile = mt * 4 + wm * 2 + mf;
                af[ks][mf] = *(const short8*)(xf
                    + ((size_t)(ktile * 16 + mtile) << 9) + (lane << 3));
            }
    };
    auto mfma = [&](const unsigned short* buf) {
        #pragma unroll
        for (int ks = 0; ks < 2; ++ks) {
            const int kb = ks * 32 + ((lane >> 4) << 3);
            short8 b0 = *(const short8*)&buf[(wn * 32 +      (lane & 15)) * RS + kb];
            short8 b1 = *(const short8*)&buf[(wn * 32 + 16 + (lane & 15)) * RS + kb];
            acc[0][0] = __builtin_amdgcn_mfma_f32_16x16x32_bf16(af[ks][0], b0, acc[0][0], 0, 0, 0);
            acc[0][1] = __builtin_amdgcn_mfma_f32_16x16x32_bf16(af[ks][0], b1, acc[0][1], 0, 0, 0);
            acc[1][0] = __builtin_amdgcn_mfma_f32_16x16x32_bf16(af[ks][1], b0, acc[1][0], 0, 0, 0);
            acc[1][1] = __builtin_amdgcn_mfma_f32_16x16x32_bf16(af[ks][1], b1, acc[1][1], 0, 0, 0);
        }
    };

    // ---- prologue: S0<-tile0, S1<-tile1, W0<-tile0 ----
    issueQA(0);                 // 18 loads
    issueQB(1);                 // 18 loads (stay in flight across KBAR)
    deqA(w0);                   // compiler waits vmcnt(18): drains qA only
    KBAR(18);                   // W0 visible; qB(tile1) still flying

    // ---- main loop: phases 0..61 (unroll-2: even issues S0, odd S1) ----
    #pragma unroll 1
    for (int ii = 0; ii < 31; ++ii) {
        const int i = ii << 1;

        // even phase: compute tile i from w0; deq S1(tile i+1)->w1; S0<-tile i+2
        loadAfr(i);             // 4 loads (oldest after qB)
        issueQA(i + 2);         // 18 loads (newest)
        deqB(w1);               // waits vmcnt(22): drains qB, keeps Afr+qA
        mfma(w0);               // waits vmcnt(18): drains Afr, keeps qA
        KBAR(18);

        // odd phase: compute tile i+1 from w1; deq S0(tile i+2)->w0; S1<-tile i+3
        loadAfr(i + 1);
        issueQB(i + 3);
        deqA(w0);
        mfma(w1);
        KBAR(18);
    }

    // ---- tail: phase 62 (deq S1(tile63)->w1), phase 63 ----
    loadAfr(62);
    deqB(w1);                   // waits qB; A-frags still in flight after
    mfma(w0);
    KBAR(0);
    loadAfr(63);
    mfma(w1);

    // ---- epilogue: C/D layout col = lane&15, row = (lane>>4)*4 + r ----
    #pragma unroll
    for (int nf = 0; nf < 2; ++nf) {
        const int n = n0 + wn * 32 + nf * 16 + (lane & 15);
        const float bv = bias[n];
        #pragma unroll
        for (int mf = 0; mf < 2; ++mf) {
            const int m0 = mt * 64 + wm * 32 + mf * 16 + ((lane >> 4) << 2);
            #pragma unroll
            for (int r = 0; r < 4; ++r)
                out[(size_t)(m0 + r) * N_DIM + n] = acc[mf][nf][r] + bv;
        }
    }
}

// ---------------- fallback (no workspace): round-1 structure ----
#define FBN 64
#define FBK 128
#define FNITER 32
#define FRS 136
__global__ __launch_bounds__(512, 2)
void plq_gemm_fb(const float* __restrict__ x,
                 const int* __restrict__ q,
                 const float* __restrict__ qs,
                 const float* __restrict__ qb,
                 const float* __restrict__ bias,
                 float* __restrict__ out)
{
    __shared__ unsigned short wlds[2][FBN * FRS];
    const int tid  = threadIdx.x;
    const int lane = tid & 63;
    const int wv   = tid >> 6;
    const int wm   = wv >> 1;
    const int wn   = wv & 1;
    const int n0   = blockIdx.x * FBN;
    const int nl = (tid & 31) * 2;
    const int kl = (tid >> 5) * 8;

    f32x4 acc[4][2] = {};
    int2   qr[8];
    float2 sv, zv;

    auto loadq = [&](int i) {
        const int* qp = q + (size_t)(i * FBK + kl) * N_DIM + (n0 + nl);
        #pragma unroll
        for (int j = 0; j < 8; ++j) qr[j] = *(const int2*)(qp + (size_t)j * N_DIM);
        sv = *(const float2*)(qs + (size_t)i * N_DIM + (n0 + nl));
        zv = *(const float2*)(qb + (size_t)i * N_DIM + (n0 + nl));
    };
    auto deqw = [&](int b) {
        union { unsigned u[4]; int4 v; } p0, p1;
        #pragma unroll
        for (int j = 0; j < 4; ++j) {
            float a0 = (float)qr[2*j].x   * sv.x + zv.x;
            float a1 = (float)qr[2*j+1].x * sv.x + zv.x;
            float c0 = (float)qr[2*j].y   * sv.y + zv.y;
            float c1 = (float)qr[2*j+1].y * sv.y + zv.y;
            p0.u[j] = (unsigned)f2bf(a0) | ((unsigned)f2bf(a1) << 16);
            p1.u[j] = (unsigned)f2bf(c0) | ((unsigned)f2bf(c1) << 16);
        }
        *(int4*)&wlds[b][(nl + 0) * FRS + kl] = p0.v;
        *(int4*)&wlds[b][(nl + 1) * FRS + kl] = p1.v;
    };
    auto compute = [&](int i, int cur) {
        short8 afr[4][4];
        #pragma unroll
        for (int ks = 0; ks < 4; ++ks)
            #pragma unroll
            for (int mf = 0; mf < 4; ++mf) {
                int m = wm * 64 + mf * 16 + (lane & 15);
                int k = i * FBK + ks * 32 + ((lane >> 4) << 3);
                const float* xp = x + (size_t)m * K_DIM + k;
                float4 lo = *(const float4*)xp;
                float4 hi = *(const float4*)(xp + 4);
                union { unsigned short s[8]; short8 v; } u;
                u.s[0] = f2bf(lo.x); u.s[1] = f2bf(lo.y); u.s[2] = f2bf(lo.z); u.s[3] = f2bf(lo.w);
                u.s[4] = f2bf(hi.x); u.s[5] = f2bf(hi.y); u.s[6] = f2bf(hi.z); u.s[7] = f2bf(hi.w);
                afr[ks][mf] = u.v;
            }
        #pragma unroll
        for (int ks = 0; ks < 4; ++ks) {
            const int kb = ks * 32 + ((lane >> 4) << 3);
            short8 b0 = *(const short8*)&wlds[cur][(wn * 32 +      (lane & 15)) * FRS + kb];
            short8 b1 = *(const short8*)&wlds[cur][(wn * 32 + 16 + (lane & 15)) * FRS + kb];
            #pragma unroll
            for (int mf = 0; mf < 4; ++mf) {
                acc[mf][0] = __builtin_amdgcn_mfma_f32_16x16x32_bf16(afr[ks][mf], b0, acc[mf][0], 0, 0, 0);
                acc[mf][1] = __builtin_amdgcn_mfma_f32_16x16x32_bf16(afr[ks][mf], b1, acc[mf][1], 0, 0, 0);
            }
        }
    };

    loadq(0); deqw(0); __syncthreads();
    for (int i = 0; i < FNITER; ++i) {
        const int cur = i & 1;
        if (i + 1 < FNITER) loadq(i + 1);
        compute(i, cur);
        if (i + 1 < FNITER) deqw(cur ^ 1);
        __syncthreads();
    }
    #pragma unroll
    for (int nf = 0; nf < 2; ++nf) {
        const int n = n0 + wn * 32 + nf * 16 + (lane & 15);
        const float bb = bias[n];
        #pragma unroll
        for (int mf = 0; mf < 4; ++mf) {
            const int m0 = wm * 64 + mf * 16 + ((lane >> 4) << 2);
            #pragma unroll
            for (int r = 0; r < 4; ++r)
                out[(size_t)(m0 + r) * N_DIM + n] = acc[mf][nf][r] + bb;
        }
    }
}

extern "C" void kernel_launch(void* const* d_in, const int* in_sizes, int n_in,
                              void* d_out, int out_size, void* d_ws, size_t ws_size,
                              hipStream_t stream) {
    const float* x    = (const float*)d_in[0];
    const int*   qk   = (const int*)d_in[1];
    const float* qs   = (const float*)d_in[2];
    const float* qb   = (const float*)d_in[3];
    const float* bias = (const float*)d_in[4];
    float* out = (float*)d_out;

    const size_t xf_bytes = (size_t)M_DIM * K_DIM * sizeof(unsigned short);
    if (ws_size >= xf_bytes) {
        unsigned short* xf = (unsigned short*)d_ws;
        convert_x_kernel<<<512, 256, 0, stream>>>(x, xf);
        const int grid = (M_DIM / BM) * (N_DIM / BN);   // 4 * 224 = 896
        plq_gemm_v8<<<grid, 256, 0, stream>>>(xf, qk, qs, qb, bias, out);
    } else {
        plq_gemm_fb<<<N_DIM / FBN, 512, 0, stream>>>(x, qk, qs, qb, bias, out);
    }
}

// Round 7
// 96.799 us; speedup vs baseline: 1.2250x; 1.2250x over previous
//
#include <hip/hip_runtime.h>
#include <hip/hip_bf16.h>

// Problem constants
#define K_DIM 4096
#define N_DIM 14336
#define M_DIM 256
#define BM 128
#define BN 64
#define BK 64
#define NPH 64          // K_DIM / BK
#define WRS 72          // W row stride in shorts (144 B = 9*16: aligned, min-conflict)

typedef __attribute__((ext_vector_type(4))) float f32x4;
typedef __attribute__((ext_vector_type(8))) short short8;

__device__ __forceinline__ unsigned short f2bf(float f) {
    union { float f; unsigned u; } v; v.f = f;
    unsigned r = v.u + 0x7fffu + ((v.u >> 16) & 1u);   // RNE
    return (unsigned short)(r >> 16);
}

__device__ __forceinline__ void glds16(const void* g, void* l) {
    __builtin_amdgcn_global_load_lds(
        (const __attribute__((address_space(1))) void*)g,
        (__attribute__((address_space(3))) void*)l, 16, 0, 0);
}

// Counted barrier: LDS visibility + drain vmem down to N (prefetch stays in flight)
#define KBAR(N) do { \
    asm volatile("s_waitcnt lgkmcnt(0)" ::: "memory");     \
    asm volatile("s_waitcnt vmcnt(" #N ")" ::: "memory");  \
    __builtin_amdgcn_s_barrier();                           \
} while (0)

// Pre-convert x (fp32 [256][4096]) into bf16 MFMA-A-fragment order:
// chunk = ktile*16 + mtile; lane l of chunk holds
// 8 bf16 = x[mtile*16 + (l&15)][ktile*32 + (l>>4)*8 .. +8]  (1 KB per chunk)
__global__ void convert_x_kernel(const float* __restrict__ x,
                                 unsigned short* __restrict__ xf) {
    int t = blockIdx.x * blockDim.x + threadIdx.x;   // 0..131071
    int chunk = t >> 6;
    int lane  = t & 63;
    int ktile = chunk >> 4;
    int mtile = chunk & 15;
    int m = mtile * 16 + (lane & 15);
    int k = ktile * 32 + ((lane >> 4) << 3);
    const float* xp = x + (size_t)m * K_DIM + k;
    float4 lo = *(const float4*)xp;
    float4 hi = *(const float4*)(xp + 4);
    union { unsigned short s[8]; int4 v; } o;
    o.s[0] = f2bf(lo.x); o.s[1] = f2bf(lo.y); o.s[2] = f2bf(lo.z); o.s[3] = f2bf(lo.w);
    o.s[4] = f2bf(hi.x); o.s[5] = f2bf(hi.y); o.s[6] = f2bf(hi.z); o.s[7] = f2bf(hi.w);
    *(int4*)(xf + ((size_t)t << 3)) = o.v;
}

// v9: 448 blocks x 512 thr (8 waves = 4m x 2n), 74 KB LDS -> 2 blocks/CU
// (16 waves/CU). q staged raw into LDS via global_load_lds, TRIPLE buffered
// (2-phase slack > HBM latency); dequant LDS->LDS; W double buffer; A-frags
// from L2-hot xf one phase early (static double set). Counted vmcnt(6)
// barriers: the hardware queue holds the prefetch, not registers.
__global__ __launch_bounds__(512, 4)
void plq_gemm_v9(const unsigned short* __restrict__ xf,
                 const int* __restrict__ q,
                 const float* __restrict__ qs,
                 const float* __restrict__ qb,
                 const float* __restrict__ bias,
                 float* __restrict__ out)
{
    __shared__ int            qt[3][BK * BN];       // 3 x 16 KB raw q tiles [k][n]
    __shared__ unsigned short wt[2][BN * WRS];      // 2 x 9 KB bf16 W tiles [n][k]
    __shared__ unsigned       szb[32 * BN];         // packed {s,z} bf16 per [g][n], 8 KB

    const int tid  = threadIdx.x;
    const int lane = tid & 63;
    const int wv   = tid >> 6;          // 0..7
    const int wm   = wv >> 1;           // 0..3 : 32 m-rows each
    const int wn   = wv & 1;            // 0..1 : 32 n-cols each

    // XCD-chunked remap (448 = 8*56): the two m-halves sharing one n-slice
    // are gid-adjacent on the same XCD -> q 2-way reuse is L2-hit.
    const int gid = (blockIdx.x & 7) * 56 + (blockIdx.x >> 3);
    const int mh  = gid & 1;
    const int n0  = (gid >> 1) * BN;

    // glds source base (per-lane): wave wv covers k-rows 8wv..8wv+7 of a tile
    const size_t qvoff = (size_t)(8 * wv + (lane >> 4)) * N_DIM + n0 + ((lane & 15) << 2);
    // dequant role: column n_d, 8 consecutive k at k0_d
    const int n_d  = tid & 63;
    const int k0_d = (tid >> 6) << 3;

    f32x4 acc[2][2] = {};
    short8 afX[2][2], afY[2][2];        // [ks][mf] static double set

    auto issueQ = [&](int t, int slot) {     // 2 glds per wave
        const int* s0 = q + (size_t)t * BK * N_DIM + qvoff;
        char* d = (char*)&qt[slot][0] + (wv << 11);
        glds16(s0, d);
        glds16(s0 + (size_t)4 * N_DIM, d + 1024);
    };
    auto loadAf = [&](int t, short8 (&af)[2][2]) {   // 4 x 16B from L2-hot xf
        #pragma unroll
        for (int ks = 0; ks < 2; ++ks)
            #pragma unroll
            for (int mf = 0; mf < 2; ++mf) {
                const int chunk = (2 * t + ks) * 16 + (mh * 8 + wm * 2 + mf);
                af[ks][mf] = *(const short8*)(xf + ((size_t)chunk << 9) + (lane << 3));
            }
    };
    auto dequant = [&](int t, int slot) {    // q[slot] -> wt[t&1]
        const int* qp = &qt[slot][0];
        int v[8];
        #pragma unroll
        for (int j = 0; j < 8; ++j) v[j] = qp[(k0_d + j) * BN + n_d];
        const unsigned szp = szb[((t >> 1) << 6) + n_d];
        union { unsigned u; float f; } su, zu;
        su.u = szp << 16;              // lo bf16 = s
        zu.u = szp & 0xffff0000u;      // hi bf16 = z
        union { unsigned u[4]; int4 vv; } pk;
        #pragma unroll
        for (int j = 0; j < 4; ++j) {
            float f0 = (float)v[2*j]   * su.f + zu.f;
            float f1 = (float)v[2*j+1] * su.f + zu.f;
            pk.u[j] = (unsigned)f2bf(f0) | ((unsigned)f2bf(f1) << 16);
        }
        *(int4*)&wt[t & 1][n_d * WRS + k0_d] = pk.vv;
    };
    auto mfma = [&](const short8 (&af)[2][2], const unsigned short* wbuf) {
        #pragma unroll
        for (int ks = 0; ks < 2; ++ks) {
            const int kb = ks * 32 + ((lane >> 4) << 3);
            short8 b0 = *(const short8*)&wbuf[(wn * 32 +      (lane & 15)) * WRS + kb];
            short8 b1 = *(const short8*)&wbuf[(wn * 32 + 16 + (lane & 15)) * WRS + kb];
            acc[0][0] = __builtin_amdgcn_mfma_f32_16x16x32_bf16(af[ks][0], b0, acc[0][0], 0, 0, 0);
            acc[0][1] = __builtin_amdgcn_mfma_f32_16x16x32_bf16(af[ks][0], b1, acc[0][1], 0, 0, 0);
            acc[1][0] = __builtin_amdgcn_mfma_f32_16x16x32_bf16(af[ks][1], b0, acc[1][0], 0, 0, 0);
            acc[1][1] = __builtin_amdgcn_mfma_f32_16x16x32_bf16(af[ks][1], b1, acc[1][1], 0, 0, 0);
        }
    };

    // ---- prologue ----
    // scales/zeros -> packed bf16 LDS (compiler waits on these loads only)
    #pragma unroll
    for (int j = 0; j < 4; ++j) {
        const int idx = tid + j * 512;          // 2048 entries = [g 0..31][n 0..63]
        const int g = idx >> 6, n = idx & 63;
        float s = qs[(size_t)g * N_DIM + n0 + n];
        float z = qb[(size_t)g * N_DIM + n0 + n];
        szb[idx] = (unsigned)f2bf(s) | ((unsigned)f2bf(z) << 16);
    }
    issueQ(0, 0);               // vm queue: q0(2)
    issueQ(1, 1);               // q0,q1 (4)
    loadAf(0, afX);             // q0,q1,afX (8)
    KBAR(6);                    // drain q0; szb visible
    dequant(0, 0);              // -> wt[0]
    issueQ(2, 2);               // queue: q1,afX,q2 (8)
    KBAR(6);                    // drain q1; wt[0] visible

    // ---- main loop: 32 x 2 phases ----
    #pragma unroll 1
    for (int ii = 0; ii < 32; ++ii) {
        const int i = ii << 1;

        // even phase p=i: compute(i) from wt[i&1] with afX
        if (i + 3 < NPH) issueQ(i + 3, (i + 3) % 3);
        loadAf(i + 1, afY);                      // i+1 <= 63 always
        dequant(i + 1, (i + 1) % 3);             // -> wt[(i+1)&1]
        mfma(afX, &wt[i & 1][0]);
        KBAR(6);

        // odd phase p=i+1: compute(i+1) from wt[(i+1)&1] with afY
        if (i + 4 < NPH) issueQ(i + 4, (i + 4) % 3);
        if (i + 2 < NPH) loadAf(i + 2, afX);
        if (i + 2 < NPH) dequant(i + 2, (i + 2) % 3);
        mfma(afY, &wt[(i + 1) & 1][0]);
        KBAR(6);
    }

    // ---- epilogue: C/D layout col = lane&15, row = (lane>>4)*4 + r ----
    #pragma unroll
    for (int nf = 0; nf < 2; ++nf) {
        const int n = n0 + wn * 32 + nf * 16 + (lane & 15);
        const float bv = bias[n];
        #pragma unroll
        for (int mf = 0; mf < 2; ++mf) {
            const int m0 = mh * BM + wm * 32 + mf * 16 + ((lane >> 4) << 2);
            #pragma unroll
            for (int r = 0; r < 4; ++r)
                out[(size_t)(m0 + r) * N_DIM + n] = acc[mf][nf][r] + bv;
        }
    }
}

// ---------------- fallback (no workspace): round-1 structure ----
#define FBN 64
#define FBK 128
#define FNITER 32
#define FRS 136
__global__ __launch_bounds__(512, 2)
void plq_gemm_fb(const float* __restrict__ x,
                 const int* __restrict__ q,
                 const float* __restrict__ qs,
                 const float* __restrict__ qb,
                 const float* __restrict__ bias,
                 float* __restrict__ out)
{
    __shared__ unsigned short wlds[2][FBN * FRS];
    const int tid  = threadIdx.x;
    const int lane = tid & 63;
    const int wv   = tid >> 6;
    const int wm   = wv >> 1;
    const int wn   = wv & 1;
    const int n0   = blockIdx.x * FBN;
    const int nl = (tid & 31) * 2;
    const int kl = (tid >> 5) * 8;

    f32x4 acc[4][2] = {};
    int2   qr[8];
    float2 sv, zv;

    auto loadq = [&](int i) {
        const int* qp = q + (size_t)(i * FBK + kl) * N_DIM + (n0 + nl);
        #pragma unroll
        for (int j = 0; j < 8; ++j) qr[j] = *(const int2*)(qp + (size_t)j * N_DIM);
        sv = *(const float2*)(qs + (size_t)i * N_DIM + (n0 + nl));
        zv = *(const float2*)(qb + (size_t)i * N_DIM + (n0 + nl));
    };
    auto deqw = [&](int b) {
        union { unsigned u[4]; int4 v; } p0, p1;
        #pragma unroll
        for (int j = 0; j < 4; ++j) {
            float a0 = (float)qr[2*j].x   * sv.x + zv.x;
            float a1 = (float)qr[2*j+1].x * sv.x + zv.x;
            float c0 = (float)qr[2*j].y   * sv.y + zv.y;
            float c1 = (float)qr[2*j+1].y * sv.y + zv.y;
            p0.u[j] = (unsigned)f2bf(a0) | ((unsigned)f2bf(a1) << 16);
            p1.u[j] = (unsigned)f2bf(c0) | ((unsigned)f2bf(c1) << 16);
        }
        *(int4*)&wlds[b][(nl + 0) * FRS + kl] = p0.v;
        *(int4*)&wlds[b][(nl + 1) * FRS + kl] = p1.v;
    };
    auto compute = [&](int i, int cur) {
        short8 afr[4][4];
        #pragma unroll
        for (int ks = 0; ks < 4; ++ks)
            #pragma unroll
            for (int mf = 0; mf < 4; ++mf) {
                int m = wm * 64 + mf * 16 + (lane & 15);
                int k = i * FBK + ks * 32 + ((lane >> 4) << 3);
                const float* xp = x + (size_t)m * K_DIM + k;
                float4 lo = *(const float4*)xp;
                float4 hi = *(const float4*)(xp + 4);
                union { unsigned short s[8]; short8 v; } u;
                u.s[0] = f2bf(lo.x); u.s[1] = f2bf(lo.y); u.s[2] = f2bf(lo.z); u.s[3] = f2bf(lo.w);
                u.s[4] = f2bf(hi.x); u.s[5] = f2bf(hi.y); u.s[6] = f2bf(hi.z); u.s[7] = f2bf(hi.w);
                afr[ks][mf] = u.v;
            }
        #pragma unroll
        for (int ks = 0; ks < 4; ++ks) {
            const int kb = ks * 32 + ((lane >> 4) << 3);
            short8 b0 = *(const short8*)&wlds[cur][(wn * 32 +      (lane & 15)) * FRS + kb];
            short8 b1 = *(const short8*)&wlds[cur][(wn * 32 + 16 + (lane & 15)) * FRS + kb];
            #pragma unroll
            for (int mf = 0; mf < 4; ++mf) {
                acc[mf][0] = __builtin_amdgcn_mfma_f32_16x16x32_bf16(afr[ks][mf], b0, acc[mf][0], 0, 0, 0);
                acc[mf][1] = __builtin_amdgcn_mfma_f32_16x16x32_bf16(afr[ks][mf], b1, acc[mf][1], 0, 0, 0);
            }
        }
    };

    loadq(0); deqw(0); __syncthreads();
    for (int i = 0; i < FNITER; ++i) {
        const int cur = i & 1;
        if (i + 1 < FNITER) loadq(i + 1);
        compute(i, cur);
        if (i + 1 < FNITER) deqw(cur ^ 1);
        __syncthreads();
    }
    #pragma unroll
    for (int nf = 0; nf < 2; ++nf) {
        const int n = n0 + wn * 32 + nf * 16 + (lane & 15);
        const float bb = bias[n];
        #pragma unroll
        for (int mf = 0; mf < 4; ++mf) {
            const int m0 = wm * 64 + mf * 16 + ((lane >> 4) << 2);
            #pragma unroll
            for (int r = 0; r < 4; ++r)
                out[(size_t)(m0 + r) * N_DIM + n] = acc[mf][nf][r] + bb;
        }
    }
}

extern "C" void kernel_launch(void* const* d_in, const int* in_sizes, int n_in,
                              void* d_out, int out_size, void* d_ws, size_t ws_size,
                              hipStream_t stream) {
    const float* x    = (const float*)d_in[0];
    const int*   qk   = (const int*)d_in[1];
    const float* qs   = (const float*)d_in[2];
    const float* qb   = (const float*)d_in[3];
    const float* bias = (const float*)d_in[4];
    float* out = (float*)d_out;

    const size_t xf_bytes = (size_t)M_DIM * K_DIM * sizeof(unsigned short);
    if (ws_size >= xf_bytes) {
        unsigned short* xf = (unsigned short*)d_ws;
        convert_x_kernel<<<512, 256, 0, stream>>>(x, xf);
        const int grid = (M_DIM / BM) * (N_DIM / BN);   // 2 * 224 = 448
        plq_gemm_v9<<<grid, 512, 0, stream>>>(xf, qk, qs, qb, bias, out);
    } else {
        plq_gemm_fb<<<N_DIM / FBN, 512, 0, stream>>>(x, qk, qs, qb, bias, out);
    }
}